// Round 3
// baseline (114.266 us; speedup 1.0000x reference)
//
#include <hip/hip_runtime.h>
#include <hip/hip_bf16.h>

// ---------------- problem constants ----------------
#define NIMG 16
#define CIN 128
#define COUT 256
#define HH 64
#define WW 64
#define KHE 7
#define KW_ 3
#define HP (HH + 6)   // 70
#define WP (WW + 2)   // 66
#define KDIM (CIN * KHE * KW_)  // 2688
#define NKT 42                  // K-tiles of 64

typedef __attribute__((ext_vector_type(8))) short short8;
typedef __attribute__((ext_vector_type(4))) float f32x4;

#define AS1(p) ((const __attribute__((address_space(1))) void*)(p))
#define AS3(p) ((__attribute__((address_space(3))) void*)(p))

// ---------------- kernel 1: pad + NCHW->NHWC transpose + f32->bf16 ----------------
__global__ void __launch_bounds__(256) pad_convert(const float* __restrict__ x,
                                                   ushort* __restrict__ xp) {
  const int bid = blockIdx.x;          // 16*70
  const int n = bid / HP, hp = bid % HP;
  const int h = hp - 3;
  ushort* dst = xp + (size_t)(n * HP + hp) * (WP * CIN);
  const int tid = threadIdx.x;

  if (h < 0 || h >= HH) {
    uint4* p = (uint4*)dst;
    uint4 z; z.x = z.y = z.z = z.w = 0u;
    for (int idx = tid; idx < (WP * CIN * 2) / 16; idx += 256) p[idx] = z;
    return;
  }

  __shared__ ushort t[CIN][WW + 1];
  for (int it = 0; it < (CIN * WW) / 256; ++it) {
    int flat = it * 256 + tid;
    int i = flat >> 6, w = flat & 63;
    float v = x[(((size_t)n * CIN + i) * HH + h) * WW + w];
    __hip_bfloat16 b = __float2bfloat16(v);
    t[i][w] = *(ushort*)&b;
  }
  __syncthreads();
  for (int it = 0; it < (WP * CIN) / 256; ++it) {
    int flat = it * 256 + tid;
    int wp = flat >> 7, i = flat & 127;
    int w = wp - 1;
    ushort v = (w < 0 || w >= WW) ? (ushort)0 : t[i][w];
    dst[flat] = v;
  }
}

// ---------------- kernel 2: build dense bf16 kernel ----------------
__global__ void __launch_bounds__(256) build_kb(const float* __restrict__ weight,
                                                const float* __restrict__ P,
                                                ushort* __restrict__ kb) {
  int idx = blockIdx.x * 256 + threadIdx.x;
  if (idx >= COUT * KW_ * CIN) return;
  int i = idx & 127;
  int kw = (idx >> 7) % 3;
  int o = idx / (KW_ * CIN);
  int base = (o * CIN + i) * 9 + kw;

  float a[KHE] = {0.f, 0.f, 0.f, 0.f, 0.f, 0.f, 0.f};
#pragma unroll
  for (int kh = 0; kh < 3; ++kh) {
    float wv = weight[base + kh * 3];
    float p = P[base + kh * 3];
    p = fminf(2.f, fmaxf(-2.f, p));
    float pos = (float)(kh + 2) + p;
    float fl = floorf(pos);
    float fr = pos - fl;
    int r0 = (int)fl;
    float c0 = wv * (1.f - fr);
    float c1 = wv * fr;
#pragma unroll
    for (int r = 0; r < KHE; ++r) {
      a[r] += ((r0 == r) ? c0 : 0.f) + ((r0 + 1 == r) ? c1 : 0.f);
    }
  }
#pragma unroll
  for (int r = 0; r < KHE; ++r) {
    __hip_bfloat16 b = __float2bfloat16(a[r]);
    kb[((size_t)(o * KHE + r) * KW_ + kw) * CIN + i] = *(ushort*)&b;
  }
}

// ---------------- kernel 3: implicit-GEMM conv, 256x256 tile, 4-phase interleave ----------------
// M = 65536, N = 256 (one tile), K = 2688 = 42 x 64
// 8 waves (2M x 4N), per-wave output 128x64, acc = 32 x f32x4
__global__ void __launch_bounds__(512, 2) dcls_gemm(const ushort* __restrict__ xp,
                                                    const ushort* __restrict__ kb,
                                                    const float* __restrict__ bias,
                                                    float* __restrict__ out) {
  __shared__ __align__(16) ushort As[2][256 * 64];   // 64 KiB
  __shared__ __align__(16) ushort Bs[2][256 * 64];   // 64 KiB

  const int tid = threadIdx.x;
  const int lane = tid & 63;
  const int wv = tid >> 6;       // 0..7
  const int wr = wv >> 2;        // 0..1 along M
  const int wc = wv & 3;         // 0..3 along N
  const int g = lane >> 4;
  const int lm = lane & 15;
  const int m0 = blockIdx.x << 8;

  // staging: 512 threads x 16B = 8KB per load-instr = 64 rows of 64 elems
  const int srow = tid >> 3;                       // row within 64-row block
  const int swz = ((tid & 7) ^ (srow & 7)) * 8;    // pre-swizzled source chunk (rule #21)

  const ushort* pA[4];
  const ushort* pB[4];
#pragma unroll
  for (int j = 0; j < 4; ++j) {
    int r = j * 64 + srow;
    int m = m0 + r;
    int ni = m >> 12, hh = (m >> 6) & 63, ww = m & 63;
    pA[j] = xp + (size_t)((ni * HP + hh) * WP + ww) * CIN + swz;
    pB[j] = kb + (size_t)r * KDIM + swz;           // o = r (single N tile)
  }

#define STAGE(c, kt) do { \
    int kh_ = (kt) / 6; int rem_ = (kt) - kh_ * 6; \
    int kw2_ = rem_ >> 1; int ic_ = rem_ & 1; \
    int offA_ = (kh_ * WP + kw2_) * CIN + ic_ * 64; \
    int offB_ = (kh_ * KW_ + kw2_) * CIN + ic_ * 64; \
    _Pragma("unroll") \
    for (int j_ = 0; j_ < 4; ++j_) \
      __builtin_amdgcn_global_load_lds(AS1(pA[j_] + offA_), AS3(&As[c][(j_ * 64 + wv * 8) * 64]), 16, 0, 0); \
    _Pragma("unroll") \
    for (int j_ = 0; j_ < 4; ++j_) \
      __builtin_amdgcn_global_load_lds(AS1(pB[j_] + offB_), AS3(&Bs[c][(j_ * 64 + wv * 8) * 64]), 16, 0, 0); \
  } while (0)

  f32x4 acc[8][4] = {};
  const int swzR = (lm & 7) << 4;   // fragment-read swizzle (row&7 == lm&7)

  short8 bf[4];   // B fragments for current kk, cached across the two mg phases
  short8 af[4];

  // one phase: optionally refresh bf (8 ds_reads) else 4; barrier; drain LDS; 16 MFMA
#define PHASE(Ab, Bb, mg, kk, READB) do { \
    if (READB) { \
      _Pragma("unroll") \
      for (int n_ = 0; n_ < 4; ++n_) { \
        int rowB_ = wc * 64 + n_ * 16 + lm; \
        bf[n_] = *(const short8*)((Bb) + rowB_ * 128 + (((kk) * 64 + g * 16) ^ swzR)); \
      } \
    } \
    _Pragma("unroll") \
    for (int m4_ = 0; m4_ < 4; ++m4_) { \
      int rowA_ = wr * 128 + (mg) * 64 + m4_ * 16 + lm; \
      af[m4_] = *(const short8*)((Ab) + rowA_ * 128 + (((kk) * 64 + g * 16) ^ swzR)); \
    } \
    __builtin_amdgcn_sched_barrier(0); \
    __builtin_amdgcn_s_barrier(); \
    asm volatile("s_waitcnt lgkmcnt(0)" ::: "memory"); \
    __builtin_amdgcn_sched_barrier(0); \
    __builtin_amdgcn_s_setprio(1); \
    _Pragma("unroll") \
    for (int m4_ = 0; m4_ < 4; ++m4_) \
      _Pragma("unroll") \
      for (int n_ = 0; n_ < 4; ++n_) \
        acc[(mg) * 4 + m4_][n_] = __builtin_amdgcn_mfma_f32_16x16x32_bf16( \
            af[m4_], bf[n_], acc[(mg) * 4 + m4_][n_], 0, 0, 0); \
    __builtin_amdgcn_s_setprio(0); \
    __builtin_amdgcn_s_barrier(); \
  } while (0)

  // prologue: stage T0, T1; wait T0 landed (T1 in flight); data-ready barrier
  STAGE(0, 0);
  STAGE(1, 1);
  asm volatile("s_waitcnt vmcnt(8)" ::: "memory");
  __builtin_amdgcn_sched_barrier(0);
  __builtin_amdgcn_s_barrier();

  for (int kt = 0; kt < NKT; ++kt) {
    const int c = kt & 1;
    const char* Ab = (const char*)&As[c][0];
    const char* Bb = (const char*)&Bs[c][0];

    PHASE(Ab, Bb, 0, 0, 1);
    PHASE(Ab, Bb, 1, 0, 0);
    PHASE(Ab, Bb, 0, 1, 1);
    PHASE(Ab, Bb, 1, 1, 0);

    // buf[c] is now free (trailing barrier of phase 4 passed by all waves)
    if (kt < NKT - 1) {
      __builtin_amdgcn_sched_barrier(0);
      if (kt + 2 < NKT) {
        STAGE(c, kt + 2);
        asm volatile("s_waitcnt vmcnt(8)" ::: "memory");  // T_{kt+1} landed, T_{kt+2} in flight
      } else {
        asm volatile("s_waitcnt vmcnt(0)" ::: "memory");  // only T_41 outstanding
      }
      __builtin_amdgcn_sched_barrier(0);
      __builtin_amdgcn_s_barrier();   // all waves' staging of next buf landed
    }
  }
#undef PHASE
#undef STAGE

  // epilogue: C/D layout col(o)=lane&15, row(m)=(lane>>4)*4+reg; fuse bias
#pragma unroll
  for (int fn = 0; fn < 4; ++fn) {
    int o = wc * 64 + fn * 16 + lm;
    float bv = bias[o];
#pragma unroll
    for (int fm = 0; fm < 8; ++fm) {
      int m = m0 + wr * 128 + fm * 16 + g * 4;
      int ni = m >> 12, hh = (m >> 6) & 63, ww = m & 63;
      f32x4 v = acc[fm][fn];
      v[0] += bv; v[1] += bv; v[2] += bv; v[3] += bv;
      *(f32x4*)(out + (size_t)((ni * COUT + o) * HH + hh) * WW + ww) = v;
    }
  }
}

// ---------------- launcher ----------------
extern "C" void kernel_launch(void* const* d_in, const int* in_sizes, int n_in,
                              void* d_out, int out_size, void* d_ws, size_t ws_size,
                              hipStream_t stream) {
  const float* x = (const float*)d_in[0];
  const float* weight = (const float*)d_in[1];
  const float* bias = (const float*)d_in[2];
  const float* P = (const float*)d_in[3];
  float* out = (float*)d_out;

  const size_t xp_elems = (size_t)NIMG * HP * WP * CIN;
  ushort* xp = (ushort*)d_ws;
  ushort* kb = (ushort*)((char*)d_ws + xp_elems * 2);

  hipLaunchKernelGGL(pad_convert, dim3(NIMG * HP), dim3(256), 0, stream, x, xp);
  hipLaunchKernelGGL(build_kb, dim3((COUT * KW_ * CIN + 255) / 256), dim3(256), 0, stream,
                     weight, P, kb);
  hipLaunchKernelGGL(dcls_gemm, dim3(65536 / 256), dim3(512), 0, stream, xp, kb, bias, out);
}

// Round 4
// 99.550 us; speedup vs baseline: 1.1478x; 1.1478x over previous
//
#include <hip/hip_runtime.h>
#include <hip/hip_bf16.h>

// ---------------- problem constants ----------------
#define NIMG 16
#define CIN 128
#define COUT 256
#define HH 64
#define WW 64
#define KHE 7
#define KW_ 3
#define HP (HH + 6)   // 70
#define WP (WW + 2)   // 66
#define KDIM (CIN * KHE * KW_)  // 2688
#define NKT 42                  // K-tiles of 64
#define NKSLICE (NKT * 2)       // 84 slices of K=32

typedef __attribute__((ext_vector_type(8))) short short8;
typedef __attribute__((ext_vector_type(4))) float f32x4;

#define AS1(p) ((const __attribute__((address_space(1))) void*)(p))
#define AS3(p) ((__attribute__((address_space(3))) void*)(p))

// ---------------- kernel 1: pad + NCHW->NHWC transpose + f32->bf16 ----------------
__global__ void __launch_bounds__(256) pad_convert(const float* __restrict__ x,
                                                   ushort* __restrict__ xp) {
  const int bid = blockIdx.x;          // 16*70
  const int n = bid / HP, hp = bid % HP;
  const int h = hp - 3;
  ushort* dst = xp + (size_t)(n * HP + hp) * (WP * CIN);
  const int tid = threadIdx.x;

  if (h < 0 || h >= HH) {
    uint4* p = (uint4*)dst;
    uint4 z; z.x = z.y = z.z = z.w = 0u;
    for (int idx = tid; idx < (WP * CIN * 2) / 16; idx += 256) p[idx] = z;
    return;
  }

  __shared__ ushort t[CIN][WW + 1];
  for (int it = 0; it < (CIN * WW) / 256; ++it) {
    int flat = it * 256 + tid;
    int i = flat >> 6, w = flat & 63;
    float v = x[(((size_t)n * CIN + i) * HH + h) * WW + w];
    __hip_bfloat16 b = __float2bfloat16(v);
    t[i][w] = *(ushort*)&b;
  }
  __syncthreads();
  for (int it = 0; it < (WP * CIN) / 256; ++it) {
    int flat = it * 256 + tid;
    int wp = flat >> 7, i = flat & 127;
    int w = wp - 1;
    ushort v = (w < 0 || w >= WW) ? (ushort)0 : t[i][w];
    dst[flat] = v;
  }
}

// ---------------- kernel 2: build dense bf16 kernel in MFMA-fragment order ----------------
// kb2[kslice][o][32] where kslice = (kh_eff*3+kw)*4 + (i>>5), within-slice = i&31.
// A wave's B-fragment (fixed n,kk) = contiguous 1KB: ((kslice*256 + o)*32 + g*8)
__global__ void __launch_bounds__(256) build_kb(const float* __restrict__ weight,
                                                const float* __restrict__ P,
                                                ushort* __restrict__ kb2) {
  int idx = blockIdx.x * 256 + threadIdx.x;
  if (idx >= COUT * KW_ * CIN) return;
  int i = idx & 127;
  int kw = (idx >> 7) % 3;
  int o = idx / (KW_ * CIN);
  int base = (o * CIN + i) * 9 + kw;

  float a[KHE] = {0.f, 0.f, 0.f, 0.f, 0.f, 0.f, 0.f};
#pragma unroll
  for (int kh = 0; kh < 3; ++kh) {
    float wv = weight[base + kh * 3];
    float p = P[base + kh * 3];
    p = fminf(2.f, fmaxf(-2.f, p));
    float pos = (float)(kh + 2) + p;
    float fl = floorf(pos);
    float fr = pos - fl;
    int r0 = (int)fl;
    float c0 = wv * (1.f - fr);
    float c1 = wv * fr;
#pragma unroll
    for (int r = 0; r < KHE; ++r) {
      a[r] += ((r0 == r) ? c0 : 0.f) + ((r0 + 1 == r) ? c1 : 0.f);
    }
  }
#pragma unroll
  for (int r = 0; r < KHE; ++r) {
    __hip_bfloat16 b = __float2bfloat16(a[r]);
    int kslice = (r * 3 + kw) * 4 + (i >> 5);
    kb2[(size_t)kslice * 8192 + o * 32 + (i & 31)] = *(ushort*)&b;
  }
}

// ---------------- kernel 3: implicit-GEMM conv; A via LDS, B via L2->regs ----------------
// M = 65536, N = 256 (one tile), K = 2688 = 42 x 64
// 8 waves (2M x 4N), per-wave output 128x64, acc = 32 x f32x4
__global__ void __launch_bounds__(512, 2) dcls_gemm(const ushort* __restrict__ xp,
                                                    const ushort* __restrict__ kb2,
                                                    const float* __restrict__ bias,
                                                    float* __restrict__ out) {
  __shared__ __align__(16) ushort As[2][256 * 64];   // 64 KiB total

  const int tid = threadIdx.x;
  const int lane = tid & 63;
  const int wv = tid >> 6;       // 0..7
  const int wr = wv >> 2;        // 0..1 along M
  const int wc = wv & 3;         // 0..3 along N
  const int g = lane >> 4;
  const int lm = lane & 15;
  const int m0 = blockIdx.x << 8;

  // A staging: 512 threads x 16B, source pre-swizzled (rule #21)
  const int srow = tid >> 3;
  const int swz = ((tid & 7) ^ (srow & 7)) * 8;

  const ushort* pA[4];
#pragma unroll
  for (int j = 0; j < 4; ++j) {
    int r = j * 64 + srow;
    int m = m0 + r;
    int ni = m >> 12, hh = (m >> 6) & 63, ww = m & 63;
    pA[j] = xp + (size_t)((ni * HP + hh) * WP + ww) * CIN + swz;
  }

  // B fragment base: lane-dependent part of ((kslice*256 + o)*32 + g*8)
  const ushort* kbB = kb2 + (size_t)wc * 2048 + lm * 32 + g * 8;

#define STAGEA(c, kt) do { \
    int kh_ = (kt) / 6; int rem_ = (kt) - kh_ * 6; \
    int kw2_ = rem_ >> 1; int ic_ = rem_ & 1; \
    int offA_ = (kh_ * WP + kw2_) * CIN + ic_ * 64; \
    _Pragma("unroll") \
    for (int j_ = 0; j_ < 4; ++j_) \
      __builtin_amdgcn_global_load_lds(AS1(pA[j_] + offA_), AS3(&As[c][(j_ * 64 + wv * 8) * 64]), 16, 0, 0); \
  } while (0)

#define LOADB(dst, kt) do { \
    _Pragma("unroll") \
    for (int n_ = 0; n_ < 4; ++n_) \
      _Pragma("unroll") \
      for (int kk_ = 0; kk_ < 2; ++kk_) \
        dst[n_][kk_] = *(const short8*)(kbB + (size_t)((kt) * 2 + kk_) * 8192 + n_ * 512); \
  } while (0)

  f32x4 acc[8][4] = {};
  const int swzR = (lm & 7) << 4;

  short8 bf0[4][2], bf1[4][2];

  // compute body for one K-tile: A-frags from As[c], B from bf (in regs)
#define TILE_MFMA(c, bf) do { \
    const char* Ab = (const char*)&As[c][0]; \
    _Pragma("unroll") \
    for (int half_ = 0; half_ < 2; ++half_) { \
      short8 af[4][2]; \
      _Pragma("unroll") \
      for (int m4_ = 0; m4_ < 4; ++m4_) \
        _Pragma("unroll") \
        for (int kk_ = 0; kk_ < 2; ++kk_) { \
          int rowA_ = wr * 128 + half_ * 64 + m4_ * 16 + lm; \
          af[m4_][kk_] = *(const short8*)(Ab + rowA_ * 128 + ((kk_ * 64 + g * 16) ^ swzR)); \
        } \
      _Pragma("unroll") \
      for (int kk_ = 0; kk_ < 2; ++kk_) \
        _Pragma("unroll") \
        for (int m4_ = 0; m4_ < 4; ++m4_) \
          _Pragma("unroll") \
          for (int n_ = 0; n_ < 4; ++n_) \
            acc[half_ * 4 + m4_][n_] = __builtin_amdgcn_mfma_f32_16x16x32_bf16( \
                af[m4_][kk_], bf[n_][kk_], acc[half_ * 4 + m4_][n_], 0, 0, 0); \
    } \
  } while (0)

  // one sub-iteration: wait A(kt)+B(kt) (oldest 12), compute, then prefetch kt+2
#define SUBITER(kt, c, bfc) do { \
    asm volatile("s_waitcnt vmcnt(12)" ::: "memory"); \
    __builtin_amdgcn_s_barrier(); \
    __builtin_amdgcn_sched_barrier(0); \
    TILE_MFMA(c, bfc); \
    int ktn_ = ((kt) + 2 < NKT) ? (kt) + 2 : 0; \
    LOADB(bfc, ktn_); \
    __builtin_amdgcn_s_barrier(); \
    __builtin_amdgcn_sched_barrier(0); \
    STAGEA(c, ktn_); \
  } while (0)

  // prologue: A(0),B(0),A(1),B(1) -> 24 outstanding
  STAGEA(0, 0);
  LOADB(bf0, 0);
  STAGEA(1, 1);
  LOADB(bf1, 1);

  for (int kt = 0; kt < NKT; kt += 2) {
    SUBITER(kt, 0, bf0);
    SUBITER(kt + 1, 1, bf1);
  }
#undef SUBITER
#undef TILE_MFMA
#undef LOADB
#undef STAGEA

  // epilogue: C/D layout col(o)=lane&15, row(m)=(lane>>4)*4+reg; fuse bias
#pragma unroll
  for (int fn = 0; fn < 4; ++fn) {
    int o = wc * 64 + fn * 16 + lm;
    float bv = bias[o];
#pragma unroll
    for (int fm = 0; fm < 8; ++fm) {
      int m = m0 + wr * 128 + fm * 16 + g * 4;
      int ni = m >> 12, hh = (m >> 6) & 63, ww = m & 63;
      f32x4 v = acc[fm][fn];
      v[0] += bv; v[1] += bv; v[2] += bv; v[3] += bv;
      *(f32x4*)(out + (size_t)((ni * COUT + o) * HH + hh) * WW + ww) = v;
    }
  }
}

// ---------------- launcher ----------------
extern "C" void kernel_launch(void* const* d_in, const int* in_sizes, int n_in,
                              void* d_out, int out_size, void* d_ws, size_t ws_size,
                              hipStream_t stream) {
  const float* x = (const float*)d_in[0];
  const float* weight = (const float*)d_in[1];
  const float* bias = (const float*)d_in[2];
  const float* P = (const float*)d_in[3];
  float* out = (float*)d_out;

  const size_t xp_elems = (size_t)NIMG * HP * WP * CIN;
  ushort* xp = (ushort*)d_ws;
  ushort* kb2 = (ushort*)((char*)d_ws + xp_elems * 2);

  hipLaunchKernelGGL(pad_convert, dim3(NIMG * HP), dim3(256), 0, stream, x, xp);
  hipLaunchKernelGGL(build_kb, dim3((COUT * KW_ * CIN + 255) / 256), dim3(256), 0, stream,
                     weight, P, kb2);
  hipLaunchKernelGGL(dcls_gemm, dim3(65536 / 256), dim3(512), 0, stream, xp, kb2, bias, out);
}